// Round 5
// baseline (56.463 us; speedup 1.0000x reference)
//
#include <hip/hip_runtime.h>
#include <hip/hip_bf16.h>

typedef short bf16x8 __attribute__((ext_vector_type(8)));
typedef float f32x4 __attribute__((ext_vector_type(4)));
typedef unsigned int uint;

#define TOTAL (64 * 16384)
#define BLOCKS (TOTAL / 256) // 4096

__device__ __forceinline__ uint bf16rne(float x) {
    uint b = __float_as_uint(x);
    return (b + 0x7fffu + ((b >> 16) & 1u)) >> 16;
}
__device__ __forceinline__ short bf16s(float x) { return (short)bf16rne(x); }
__device__ __forceinline__ uint pk2(float lo, float hi) {
    __hip_bfloat162 h2 = __float22bfloat162_rn(make_float2(lo, hi));
    uint u;
    __builtin_memcpy(&u, &h2, sizeof(u));
    return u;
}
__device__ __forceinline__ float relu_(float x) { return fmaxf(x, 0.0f); }
__device__ __forceinline__ float fast_sigmoid(float x) {
    return __builtin_amdgcn_rcpf(1.0f + __expf(-x));
}
__device__ __forceinline__ uint bperm(int addr, uint v) {
    return __builtin_amdgcn_ds_bpermute(addr, v); // addr = srcLane*4
}

// B-frag for a 16-unit activation tile from packed lo/hi C-frag uints.
// dest lane (g,c) k=8g+i; valid for g<2 (g>=2 garbage -> needs zero A weights)
__device__ __forceinline__ bf16x8 asm16(uint lo, uint hi, int aA, int aB) {
    uint4 u;
    u.x = bperm(aA, lo);
    u.y = bperm(aA, hi);
    u.z = bperm(aB, lo);
    u.w = bperm(aB, hi);
    bf16x8 r;
    __builtin_memcpy(&r, &u, sizeof(r));
    return r;
}
// B-frag for a 32-unit activation (f0 = units 0-15, f1 = units 16-31), all g valid
__device__ __forceinline__ bf16x8 asm32(uint lo0, uint hi0, uint lo1, uint hi1,
                                        int aA, int aB, bool glo) {
    uint t0, t1;
    uint4 u;
    t0 = bperm(aA, lo0); t1 = bperm(aA, lo1); u.x = glo ? t0 : t1;
    t0 = bperm(aA, hi0); t1 = bperm(aA, hi1); u.y = glo ? t0 : t1;
    t0 = bperm(aB, lo0); t1 = bperm(aB, lo1); u.z = glo ? t0 : t1;
    t0 = bperm(aB, hi0); t1 = bperm(aB, hi1); u.w = glo ? t0 : t1;
    bf16x8 r;
    __builtin_memcpy(&r, &u, sizeof(r));
    return r;
}

// ---------------- global max of criticality -> ws[0] (as uint bits) ----------
__global__ __launch_bounds__(256) void crit_max_kernel(
        const float* __restrict__ crit, unsigned int* __restrict__ ws, int n4) {
    __shared__ float smax[4];
    const int tid = threadIdx.x;
    float m = 0.0f;
    const float4* c4 = (const float4*)crit;
    for (int i = blockIdx.x * 256 + tid; i < n4; i += gridDim.x * 256) {
        float4 v = c4[i];
        m = fmaxf(fmaxf(m, v.x), fmaxf(fmaxf(v.y, v.z), v.w));
    }
#pragma unroll
    for (int off = 32; off > 0; off >>= 1)
        m = fmaxf(m, __shfl_xor(m, off));
    if ((tid & 63) == 0) smax[tid >> 6] = m;
    __syncthreads();
    if (tid == 0) {
        m = fmaxf(fmaxf(smax[0], smax[1]), fmaxf(smax[2], smax[3]));
        atomicMax(ws, __float_as_uint(m));
    }
}

// ---------------- fused MFMA risk kernel (register-only, no LDS) -------------
__global__ __launch_bounds__(256, 4) void risk_mfma_kernel(
        const float* __restrict__ tp,   const float* __restrict__ crit,
        const float* __restrict__ conn, const float* __restrict__ sens,
        const float* __restrict__ bv,   const float* __restrict__ dsv,
        const float* __restrict__ comp, const float* __restrict__ rt,
        const float* __restrict__ sev,
        const float* __restrict__ ctxW1, const float* __restrict__ ctxb1,
        const float* __restrict__ ctxW2, const float* __restrict__ ctxb2,
        const float* __restrict__ ctxW3, const float* __restrict__ ctxb3,
        const float* __restrict__ pW1,  const float* __restrict__ pb1,
        const float* __restrict__ pW2,  const float* __restrict__ pb2,
        const float* __restrict__ pW3,  const float* __restrict__ pb3,
        const float* __restrict__ pWo,  const float* __restrict__ pbo,
        const float* __restrict__ w_threat, const float* __restrict__ w_impact,
        const float* __restrict__ w_vuln,   const float* __restrict__ w_ctx,
        const unsigned int* __restrict__ ws_max,
        float* __restrict__ out) {
    const int lane = threadIdx.x & 63;
    const int g    = lane >> 4;   // 0..3
    const int c    = lane & 15;   // 0..15
    const bool glo = (g < 2);
    const int aA   = (((g & 1) * 32) + c) * 4; // bpermute src addr (bytes)
    const int aB   = aA + 64;

    const bf16x8 z8 = {0,0,0,0,0,0,0,0};
    const f32x4  z4 = {0.f,0.f,0.f,0.f};

    // ---- uniform scalars ----
    const float m   = __uint_as_float(ws_max[0]);
    const float wt  = w_threat[0], wi = w_impact[0], wv = w_vuln[0], wc = w_ctx[0];
    const float inv_tw = 1.0f / (wt + wi + wv + wc);
    const float inv_md = 1.0f / fmaxf(m, 1e-12f);
    const float wcn = wc * inv_tw;
    const float cb3 = ctxb3[0];
    const float pbo0 = pbo[0];

    // ---- weight fragments (A operand: row = out-unit = lane&15, k = 8*g+i) --
    bf16x8 w1f[4];
#pragma unroll
    for (int nt = 0; nt < 4; ++nt) {
        bf16x8 f = z8;
        if (g == 0) {
#pragma unroll
            for (int i = 0; i < 4; ++i) f[i] = bf16s(pW1[i * 64 + nt * 16 + c]);
            f[4] = bf16s(pb1[nt * 16 + c]);
        }
        w1f[nt] = f;
    }
    bf16x8 w2f[2][2];
#pragma unroll
    for (int nt = 0; nt < 2; ++nt)
#pragma unroll
        for (int kf = 0; kf < 2; ++kf) {
            bf16x8 f;
#pragma unroll
            for (int i = 0; i < 8; ++i) {
                int k = kf * 32 + 8 * g + i;
                f[i] = bf16s(pW2[k * 32 + nt * 16 + c]);
            }
            w2f[nt][kf] = f;
        }
    bf16x8 w3f;
#pragma unroll
    for (int i = 0; i < 8; ++i) w3f[i] = bf16s(pW3[(8 * g + i) * 16 + c]);
    bf16x8 cw1f = z8;
    if (g == 0) {
#pragma unroll
        for (int i = 0; i < 4; ++i) cw1f[i] = bf16s(ctxW1[i * 16 + c]);
        cw1f[4] = bf16s(ctxb1[c]);
    }
    bf16x8 cw2f = z8;
    if (g < 2) {
#pragma unroll
        for (int i = 0; i < 8; ++i) {
            int k = 8 * g + i;
            cw2f[i] = (c < 8) ? bf16s(ctxW2[k * 8 + c]) : (short)0;
        }
    }
    f32x4 b2i[2];
#pragma unroll
    for (int nt = 0; nt < 2; ++nt) {
        float4 t = ((const float4*)pb2)[nt * 4 + g];
        b2i[nt] = (f32x4){t.x, t.y, t.z, t.w};
    }
    float4 t3 = ((const float4*)pb3)[g];
    f32x4 b3i = (f32x4){t3.x, t3.y, t3.z, t3.w};
    f32x4 cb2i = z4;
    float4 cw3v = make_float4(0.f, 0.f, 0.f, 0.f);
    if (g < 2) {
        float4 tb = ((const float4*)ctxb2)[g];
        cb2i = (f32x4){tb.x, tb.y, tb.z, tb.w};
        cw3v = ((const float4*)ctxW3)[g];
    }
    float4 wog = ((const float4*)pWo)[g];

    const int ewave = blockIdx.x * 256 + (int)(threadIdx.x >> 6) * 64;

    // ---------------- phase 1: per-element components (64-wide, in regs) -----
    uint fvx, fvy, fvz, fvw;
    float pbase;
    {
        const int e = ewave + lane;
        float tpv = tp[e], cv = crit[e], cnv = conn[e], snv = sens[e];
        float bvv = bv[e], dvv = dsv[e], cpv = comp[e], rtv = rt[e], svv = sev[e];
        float threat = fast_sigmoid(3.0f * tpv);
        float impact = (m > 0.0f) ? cv * inv_md : cv;
        float vuln   = svv * 0.1f;
        float invrt  = __builtin_amdgcn_rcpf(rtv + 1e-6f);
        pbase = (wt * threat + wi * impact + wv * vuln) * inv_tw;
        fvx = pk2(bvv, dvv);   // k0=bv, k1=dsv
        fvy = pk2(cpv, invrt); // k2=comp, k3=1/rt
        fvz = pk2(1.0f, cv);   // k4=1.0(bias), k5=crit
        fvw = pk2(cnv, snv);   // k6=conn, k7=sens
    }
    // ---------------- phase 2: 4 independent register-only tiles -------------
    float ovs[4];
#pragma unroll
    for (int t = 0; t < 4; ++t) {
        const int aF = (t * 16 + c) * 4; // feature source lane
        // gather features of element t*16+c into every lane
        uint4 fr;
        fr.x = bperm(aF, fvx);
        fr.y = bperm(aF, fvy);
        fr.z = bperm(aF, fvz);
        fr.w = bperm(aF, fvw);
        float pb = __uint_as_float(bperm(aF, __float_as_uint(pbase)));
        bf16x8 bctx;
        __builtin_memcpy(&bctx, &fr, sizeof(bctx));
        // ctx L1: 4->16 (+bias via k=4)
        f32x4 cc1 = __builtin_amdgcn_mfma_f32_16x16x32_bf16(cw1f, bctx, z4, 0, 0, 0);
        uint c1lo = pk2(relu_(cc1[0]), relu_(cc1[1]));
        uint c1hi = pk2(relu_(cc1[2]), relu_(cc1[3]));
        // ctx L2: 16->8 (K=16 real; g>=2 garbage hits zero weights)
        bf16x8 b2c = asm16(c1lo, c1hi, aA, aB);
        f32x4 cc2 = __builtin_amdgcn_mfma_f32_16x16x32_bf16(cw2f, b2c, cb2i, 0, 0, 0);
        float pc = fmaf(relu_(cc2[0]), cw3v.x, fmaf(relu_(cc2[1]), cw3v.y,
                   fmaf(relu_(cc2[2]), cw3v.z, relu_(cc2[3]) * cw3v.w)));
        pc += __shfl_xor(pc, 16);
        pc += __shfl_xor(pc, 32);
        float ctxr = fast_sigmoid(pc + cb3);
        float base = fmaf(wcn, ctxr, pb);
        // prop L1 B-frag: [base, crit, conn, sens, 1.0, 0,0,0]
        uint4 pfu;
        pfu.x = bf16rne(base) | (fr.z & 0xffff0000u);
        pfu.y = fr.w;
        pfu.z = 0x3f80u;
        pfu.w = 0u;
        bf16x8 bp;
        __builtin_memcpy(&bp, &pfu, sizeof(bp));
        // prop L1: 4->64
        uint l1lo[4], l1hi[4];
#pragma unroll
        for (int nt = 0; nt < 4; ++nt) {
            f32x4 c1 = __builtin_amdgcn_mfma_f32_16x16x32_bf16(w1f[nt], bp, z4, 0, 0, 0);
            l1lo[nt] = pk2(relu_(c1[0]), relu_(c1[1]));
            l1hi[nt] = pk2(relu_(c1[2]), relu_(c1[3]));
        }
        // prop L2: 64->32
        bf16x8 a0 = asm32(l1lo[0], l1hi[0], l1lo[1], l1hi[1], aA, aB, glo);
        bf16x8 a1 = asm32(l1lo[2], l1hi[2], l1lo[3], l1hi[3], aA, aB, glo);
        f32x4 c2[2];
#pragma unroll
        for (int nt = 0; nt < 2; ++nt) {
            f32x4 acc = __builtin_amdgcn_mfma_f32_16x16x32_bf16(w2f[nt][0], a0, b2i[nt], 0, 0, 0);
            c2[nt] = __builtin_amdgcn_mfma_f32_16x16x32_bf16(w2f[nt][1], a1, acc, 0, 0, 0);
        }
        uint l2lo0 = pk2(relu_(c2[0][0]), relu_(c2[0][1]));
        uint l2hi0 = pk2(relu_(c2[0][2]), relu_(c2[0][3]));
        uint l2lo1 = pk2(relu_(c2[1][0]), relu_(c2[1][1]));
        uint l2hi1 = pk2(relu_(c2[1][2]), relu_(c2[1][3]));
        // prop L3: 32->16
        bf16x8 a3 = asm32(l2lo0, l2hi0, l2lo1, l2hi1, aA, aB, glo);
        f32x4 c3 = __builtin_amdgcn_mfma_f32_16x16x32_bf16(w3f, a3, b3i, 0, 0, 0);
        // output layer 16->1 + sigmoid
        float p = fmaf(relu_(c3[0]), wog.x, fmaf(relu_(c3[1]), wog.y,
                  fmaf(relu_(c3[2]), wog.z, relu_(c3[3]) * wog.w)));
        p += __shfl_xor(p, 16);
        p += __shfl_xor(p, 32);
        ovs[t] = fast_sigmoid(p + pbo0);
    }
    // lane (g,c) stores element ewave + g*16 + c == ewave + lane (coalesced)
    float ov = (g == 0) ? ovs[0] : (g == 1) ? ovs[1] : (g == 2) ? ovs[2] : ovs[3];
    out[ewave + lane] = ov;
}

extern "C" void kernel_launch(void* const* d_in, const int* in_sizes, int n_in,
                              void* d_out, int out_size, void* d_ws, size_t ws_size,
                              hipStream_t stream) {
    const float* tp    = (const float*)d_in[0];
    const float* crit  = (const float*)d_in[1];
    const float* conn  = (const float*)d_in[2];
    const float* sens  = (const float*)d_in[3];
    const float* bv    = (const float*)d_in[4];
    const float* dsv   = (const float*)d_in[5];
    const float* comp  = (const float*)d_in[6];
    const float* rt    = (const float*)d_in[7];
    const float* sev   = (const float*)d_in[8];
    const float* ctxW1 = (const float*)d_in[9];
    const float* ctxb1 = (const float*)d_in[10];
    const float* ctxW2 = (const float*)d_in[11];
    const float* ctxb2 = (const float*)d_in[12];
    const float* ctxW3 = (const float*)d_in[13];
    const float* ctxb3 = (const float*)d_in[14];
    const float* pW1   = (const float*)d_in[15];
    const float* pb1   = (const float*)d_in[16];
    const float* pW2   = (const float*)d_in[17];
    const float* pb2   = (const float*)d_in[18];
    const float* pW3   = (const float*)d_in[19];
    const float* pb3   = (const float*)d_in[20];
    const float* pWo   = (const float*)d_in[21];
    const float* pbo   = (const float*)d_in[22];
    const float* w_t   = (const float*)d_in[23];
    const float* w_i   = (const float*)d_in[24];
    const float* w_v   = (const float*)d_in[25];
    const float* w_c   = (const float*)d_in[26];

    unsigned int* ws_max = (unsigned int*)d_ws;
    float* out = (float*)d_out;

    (void)hipMemsetAsync(ws_max, 0, sizeof(unsigned int), stream);
    crit_max_kernel<<<256, 256, 0, stream>>>(crit, ws_max, TOTAL / 4);
    risk_mfma_kernel<<<BLOCKS, 256, 0, stream>>>(
        tp, crit, conn, sens, bv, dsv, comp, rt, sev,
        ctxW1, ctxb1, ctxW2, ctxb2, ctxW3, ctxb3,
        pW1, pb1, pW2, pb2, pW3, pb3, pWo, pbo,
        w_t, w_i, w_v, w_c, ws_max, out);
}

// Round 6
// 52.836 us; speedup vs baseline: 1.0686x; 1.0686x over previous
//
#include <hip/hip_runtime.h>
#include <hip/hip_bf16.h>

typedef short bf16x8 __attribute__((ext_vector_type(8)));
typedef float f32x4 __attribute__((ext_vector_type(4)));
typedef unsigned int uint;

#define TOTAL (64 * 16384)
#define ITERS 4
#define BLOCKS (TOTAL / (256 * ITERS)) // 1024

__device__ __forceinline__ uint bf16rne(float x) {
    uint b = __float_as_uint(x);
    return (b + 0x7fffu + ((b >> 16) & 1u)) >> 16;
}
__device__ __forceinline__ short bf16s(float x) { return (short)bf16rne(x); }
__device__ __forceinline__ uint pk2(float lo, float hi) {
    __hip_bfloat162 h2 = __float22bfloat162_rn(make_float2(lo, hi));
    uint u;
    __builtin_memcpy(&u, &h2, sizeof(u));
    return u;
}
__device__ __forceinline__ float relu_(float x) { return fmaxf(x, 0.0f); }
__device__ __forceinline__ float fast_sigmoid(float x) {
    return __builtin_amdgcn_rcpf(1.0f + __expf(-x));
}
__device__ __forceinline__ uint bperm(int addr, uint v) {
    return __builtin_amdgcn_ds_bpermute(addr, v);
}
__device__ __forceinline__ float dot4r(f32x4 v, float4 w) {
    return fmaf(relu_(v[0]), w.x, fmaf(relu_(v[1]), w.y,
           fmaf(relu_(v[2]), w.z, relu_(v[3]) * w.w)));
}

// B-frag for a 16-unit activation tile from packed lo/hi C-frag uints.
__device__ __forceinline__ bf16x8 asm16(uint lo, uint hi, int aA, int aB) {
    uint4 u;
    u.x = bperm(aA, lo);
    u.y = bperm(aA, hi);
    u.z = bperm(aB, lo);
    u.w = bperm(aB, hi);
    bf16x8 r;
    __builtin_memcpy(&r, &u, sizeof(r));
    return r;
}
// B-frag for a 32-unit activation (f0 = units 0-15, f1 = units 16-31)
__device__ __forceinline__ bf16x8 asm32(uint lo0, uint hi0, uint lo1, uint hi1,
                                        int aA, int aB, bool glo) {
    uint t0, t1;
    uint4 u;
    t0 = bperm(aA, lo0); t1 = bperm(aA, lo1); u.x = glo ? t0 : t1;
    t0 = bperm(aA, hi0); t1 = bperm(aA, hi1); u.y = glo ? t0 : t1;
    t0 = bperm(aB, lo0); t1 = bperm(aB, lo1); u.z = glo ? t0 : t1;
    t0 = bperm(aB, hi0); t1 = bperm(aB, hi1); u.w = glo ? t0 : t1;
    bf16x8 r;
    __builtin_memcpy(&r, &u, sizeof(r));
    return r;
}

// ---------------- global max of criticality -> ws[0] (as uint bits) ----------
__global__ __launch_bounds__(256) void crit_max_kernel(
        const float* __restrict__ crit, unsigned int* __restrict__ ws, int n4) {
    __shared__ float smax[4];
    const int tid = threadIdx.x;
    float m = 0.0f;
    const float4* c4 = (const float4*)crit;
    for (int i = blockIdx.x * 256 + tid; i < n4; i += gridDim.x * 256) {
        float4 v = c4[i];
        m = fmaxf(fmaxf(m, v.x), fmaxf(fmaxf(v.y, v.z), v.w));
    }
#pragma unroll
    for (int off = 32; off > 0; off >>= 1)
        m = fmaxf(m, __shfl_xor(m, off));
    if ((tid & 63) == 0) smax[tid >> 6] = m;
    __syncthreads();
    if (tid == 0) {
        m = fmaxf(fmaxf(smax[0], smax[1]), fmaxf(smax[2], smax[3]));
        atomicMax(ws, __float_as_uint(m));
    }
}

// ------- fused MFMA risk kernel (register-only, staged cross-tile ILP) -------
__global__ __launch_bounds__(256, 3) void risk_mfma_kernel(
        const float* __restrict__ tp,   const float* __restrict__ crit,
        const float* __restrict__ conn, const float* __restrict__ sens,
        const float* __restrict__ bv,   const float* __restrict__ dsv,
        const float* __restrict__ comp, const float* __restrict__ rt,
        const float* __restrict__ sev,
        const float* __restrict__ ctxW1, const float* __restrict__ ctxb1,
        const float* __restrict__ ctxW2, const float* __restrict__ ctxb2,
        const float* __restrict__ ctxW3, const float* __restrict__ ctxb3,
        const float* __restrict__ pW1,  const float* __restrict__ pb1,
        const float* __restrict__ pW2,  const float* __restrict__ pb2,
        const float* __restrict__ pW3,  const float* __restrict__ pb3,
        const float* __restrict__ pWo,  const float* __restrict__ pbo,
        const float* __restrict__ w_threat, const float* __restrict__ w_impact,
        const float* __restrict__ w_vuln,   const float* __restrict__ w_ctx,
        const unsigned int* __restrict__ ws_max,
        float* __restrict__ out) {
    const int lane = threadIdx.x & 63;
    const int g    = lane >> 4;   // 0..3
    const int c    = lane & 15;   // 0..15
    const bool glo = (g < 2);
    const int aA   = (((g & 1) * 32) + c) * 4;
    const int aB   = aA + 64;

    const bf16x8 z8 = {0,0,0,0,0,0,0,0};
    const f32x4  z4 = {0.f,0.f,0.f,0.f};

    // ---- uniform scalars ----
    const float m   = __uint_as_float(ws_max[0]);
    const float wt  = w_threat[0], wi = w_impact[0], wv = w_vuln[0], wc = w_ctx[0];
    const float inv_tw = 1.0f / (wt + wi + wv + wc);
    const float inv_md = 1.0f / fmaxf(m, 1e-12f);
    const float wcn = wc * inv_tw;
    const float cb3 = ctxb3[0];
    const float pbo0 = pbo[0];

    // ---- weight fragments (A operand: row = out-unit = lane&15, k = 8*g+i) --
    bf16x8 w1f[4];
#pragma unroll
    for (int nt = 0; nt < 4; ++nt) {
        bf16x8 f = z8;
        if (g == 0) {
#pragma unroll
            for (int i = 0; i < 4; ++i) f[i] = bf16s(pW1[i * 64 + nt * 16 + c]);
            f[4] = bf16s(pb1[nt * 16 + c]);
        }
        w1f[nt] = f;
    }
    bf16x8 w2f[2][2];
#pragma unroll
    for (int nt = 0; nt < 2; ++nt)
#pragma unroll
        for (int kf = 0; kf < 2; ++kf) {
            bf16x8 f;
#pragma unroll
            for (int i = 0; i < 8; ++i) {
                int k = kf * 32 + 8 * g + i;
                f[i] = bf16s(pW2[k * 32 + nt * 16 + c]);
            }
            w2f[nt][kf] = f;
        }
    bf16x8 w3f;
#pragma unroll
    for (int i = 0; i < 8; ++i) w3f[i] = bf16s(pW3[(8 * g + i) * 16 + c]);
    bf16x8 cw1f = z8;
    if (g == 0) {
#pragma unroll
        for (int i = 0; i < 4; ++i) cw1f[i] = bf16s(ctxW1[i * 16 + c]);
        cw1f[4] = bf16s(ctxb1[c]);
    }
    bf16x8 cw2f = z8;
    if (g < 2) {
#pragma unroll
        for (int i = 0; i < 8; ++i) {
            int k = 8 * g + i;
            cw2f[i] = (c < 8) ? bf16s(ctxW2[k * 8 + c]) : (short)0;
        }
    }
    f32x4 b2i[2];
#pragma unroll
    for (int nt = 0; nt < 2; ++nt) {
        float4 t = ((const float4*)pb2)[nt * 4 + g];
        b2i[nt] = (f32x4){t.x, t.y, t.z, t.w};
    }
    float4 t3 = ((const float4*)pb3)[g];
    f32x4 b3i = (f32x4){t3.x, t3.y, t3.z, t3.w};
    f32x4 cb2i = z4;
    float4 cw3v = make_float4(0.f, 0.f, 0.f, 0.f);
    if (g < 2) {
        float4 tb = ((const float4*)ctxb2)[g];
        cb2i = (f32x4){tb.x, tb.y, tb.z, tb.w};
        cw3v = ((const float4*)ctxW3)[g];
    }
    float4 wog = ((const float4*)pWo)[g];

    const int eblock = blockIdx.x * (256 * ITERS);

#pragma unroll 1
    for (int it = 0; it < ITERS; ++it) {
        const int ewave = eblock + it * 256 + (int)(threadIdx.x >> 6) * 64;
        // -------- phase 1: per-element components (64-wide, in regs) ---------
        uint fvx, fvy, fvz, fvw;
        float pbase;
        {
            const int e = ewave + lane;
            float tpv = tp[e], cv = crit[e], cnv = conn[e], snv = sens[e];
            float bvv = bv[e], dvv = dsv[e], cpv = comp[e], rtv = rt[e], svv = sev[e];
            float threat = fast_sigmoid(3.0f * tpv);
            float impact = (m > 0.0f) ? cv * inv_md : cv;
            float vuln   = svv * 0.1f;
            float invrt  = __builtin_amdgcn_rcpf(rtv + 1e-6f);
            pbase = (wt * threat + wi * impact + wv * vuln) * inv_tw;
            fvx = pk2(bvv, dvv);
            fvy = pk2(cpv, invrt);
            fvz = pk2(1.0f, cv);
            fvw = pk2(cnv, snv);
        }
        // -------- phase 2: staged, 4 tiles advance together (ILP=4) ----------
        // Stage A: feature gathers (20 DS ops in flight)
        uint4 fr[4];
        float pb[4];
#pragma unroll
        for (int t = 0; t < 4; ++t) {
            const int aF = (t * 16 + c) * 4;
            fr[t].x = bperm(aF, fvx);
            fr[t].y = bperm(aF, fvy);
            fr[t].z = bperm(aF, fvz);
            fr[t].w = bperm(aF, fvw);
            pb[t] = __uint_as_float(bperm(aF, __float_as_uint(pbase)));
        }
        // Stage B: ctx L1 MFMA + pack
        uint c1lo[4], c1hi[4];
#pragma unroll
        for (int t = 0; t < 4; ++t) {
            bf16x8 bctx;
            __builtin_memcpy(&bctx, &fr[t], sizeof(bctx));
            f32x4 cc1 = __builtin_amdgcn_mfma_f32_16x16x32_bf16(cw1f, bctx, z4, 0, 0, 0);
            c1lo[t] = pk2(relu_(cc1[0]), relu_(cc1[1]));
            c1hi[t] = pk2(relu_(cc1[2]), relu_(cc1[3]));
        }
        // Stage C: asm16 + ctx L2 MFMA + partial dot
        float pcv[4];
#pragma unroll
        for (int t = 0; t < 4; ++t) {
            bf16x8 b2c = asm16(c1lo[t], c1hi[t], aA, aB);
            f32x4 cc2 = __builtin_amdgcn_mfma_f32_16x16x32_bf16(cw2f, b2c, cb2i, 0, 0, 0);
            pcv[t] = dot4r(cc2, cw3v);
        }
        // Stage D: cross-group reduce + sigmoid + base + prop-L1 B-frag
        bf16x8 bpv[4];
#pragma unroll
        for (int t = 0; t < 4; ++t) {
            float pc = pcv[t];
            pc += __shfl_xor(pc, 16);
            pc += __shfl_xor(pc, 32);
            float ctxr = fast_sigmoid(pc + cb3);
            float base = fmaf(wcn, ctxr, pb[t]);
            uint4 pfu;
            pfu.x = bf16rne(base) | (fr[t].z & 0xffff0000u);
            pfu.y = fr[t].w;
            pfu.z = 0x3f80u;
            pfu.w = 0u;
            __builtin_memcpy(&bpv[t], &pfu, sizeof(bf16x8));
        }
        // Stage E: prop L1 (16 MFMA) + pack
        uint l1lo[4][4], l1hi[4][4];
#pragma unroll
        for (int t = 0; t < 4; ++t)
#pragma unroll
            for (int nt = 0; nt < 4; ++nt) {
                f32x4 c1 = __builtin_amdgcn_mfma_f32_16x16x32_bf16(w1f[nt], bpv[t], z4, 0, 0, 0);
                l1lo[t][nt] = pk2(relu_(c1[0]), relu_(c1[1]));
                l1hi[t][nt] = pk2(relu_(c1[2]), relu_(c1[3]));
            }
        // Stage F: asm32 x2 per tile (32 DS ops)
        bf16x8 a0[4], a1[4];
#pragma unroll
        for (int t = 0; t < 4; ++t) {
            a0[t] = asm32(l1lo[t][0], l1hi[t][0], l1lo[t][1], l1hi[t][1], aA, aB, glo);
            a1[t] = asm32(l1lo[t][2], l1hi[t][2], l1lo[t][3], l1hi[t][3], aA, aB, glo);
        }
        // Stage G: prop L2 (16 MFMA) + pack
        uint l2lo[4][2], l2hi[4][2];
#pragma unroll
        for (int t = 0; t < 4; ++t)
#pragma unroll
            for (int nt = 0; nt < 2; ++nt) {
                f32x4 acc = __builtin_amdgcn_mfma_f32_16x16x32_bf16(w2f[nt][0], a0[t], b2i[nt], 0, 0, 0);
                f32x4 c2  = __builtin_amdgcn_mfma_f32_16x16x32_bf16(w2f[nt][1], a1[t], acc, 0, 0, 0);
                l2lo[t][nt] = pk2(relu_(c2[0]), relu_(c2[1]));
                l2hi[t][nt] = pk2(relu_(c2[2]), relu_(c2[3]));
            }
        // Stage H: asm32 + prop L3 MFMA + epilogue dot
        float pv[4];
#pragma unroll
        for (int t = 0; t < 4; ++t) {
            bf16x8 a3 = asm32(l2lo[t][0], l2hi[t][0], l2lo[t][1], l2hi[t][1], aA, aB, glo);
            f32x4 c3 = __builtin_amdgcn_mfma_f32_16x16x32_bf16(w3f, a3, b3i, 0, 0, 0);
            pv[t] = dot4r(c3, wog);
        }
        // Stage I: reduce + sigmoid + coalesced store
        float ovs[4];
#pragma unroll
        for (int t = 0; t < 4; ++t) {
            float p = pv[t];
            p += __shfl_xor(p, 16);
            p += __shfl_xor(p, 32);
            ovs[t] = fast_sigmoid(p + pbo0);
        }
        float ov = (g == 0) ? ovs[0] : (g == 1) ? ovs[1] : (g == 2) ? ovs[2] : ovs[3];
        out[ewave + lane] = ov;
    }
}

extern "C" void kernel_launch(void* const* d_in, const int* in_sizes, int n_in,
                              void* d_out, int out_size, void* d_ws, size_t ws_size,
                              hipStream_t stream) {
    const float* tp    = (const float*)d_in[0];
    const float* crit  = (const float*)d_in[1];
    const float* conn  = (const float*)d_in[2];
    const float* sens  = (const float*)d_in[3];
    const float* bv    = (const float*)d_in[4];
    const float* dsv   = (const float*)d_in[5];
    const float* comp  = (const float*)d_in[6];
    const float* rt    = (const float*)d_in[7];
    const float* sev   = (const float*)d_in[8];
    const float* ctxW1 = (const float*)d_in[9];
    const float* ctxb1 = (const float*)d_in[10];
    const float* ctxW2 = (const float*)d_in[11];
    const float* ctxb2 = (const float*)d_in[12];
    const float* ctxW3 = (const float*)d_in[13];
    const float* ctxb3 = (const float*)d_in[14];
    const float* pW1   = (const float*)d_in[15];
    const float* pb1   = (const float*)d_in[16];
    const float* pW2   = (const float*)d_in[17];
    const float* pb2   = (const float*)d_in[18];
    const float* pW3   = (const float*)d_in[19];
    const float* pb3   = (const float*)d_in[20];
    const float* pWo   = (const float*)d_in[21];
    const float* pbo   = (const float*)d_in[22];
    const float* w_t   = (const float*)d_in[23];
    const float* w_i   = (const float*)d_in[24];
    const float* w_v   = (const float*)d_in[25];
    const float* w_c   = (const float*)d_in[26];

    unsigned int* ws_max = (unsigned int*)d_ws;
    float* out = (float*)d_out;

    (void)hipMemsetAsync(ws_max, 0, sizeof(unsigned int), stream);
    crit_max_kernel<<<256, 256, 0, stream>>>(crit, ws_max, TOTAL / 4);
    risk_mfma_kernel<<<BLOCKS, 256, 0, stream>>>(
        tp, crit, conn, sens, bv, dsv, comp, rt, sev,
        ctxW1, ctxb1, ctxW2, ctxb2, ctxW3, ctxb3,
        pW1, pb1, pW2, pb2, pW3, pb3, pWo, pbo,
        w_t, w_i, w_v, w_c, ws_max, out);
}

// Round 7
// 44.439 us; speedup vs baseline: 1.2706x; 1.1890x over previous
//
#include <hip/hip_runtime.h>
#include <hip/hip_bf16.h>

typedef short bf16x8 __attribute__((ext_vector_type(8)));
typedef float f32x4 __attribute__((ext_vector_type(4)));
typedef unsigned int uint;

#define TOTAL (64 * 16384)
#define ITERS 2
#define BLOCKS (TOTAL / (256 * ITERS)) // 2048

__device__ __forceinline__ uint bf16rne(float x) {
    uint b = __float_as_uint(x);
    return (b + 0x7fffu + ((b >> 16) & 1u)) >> 16;
}
__device__ __forceinline__ short bf16s(float x) { return (short)bf16rne(x); }
__device__ __forceinline__ uint pk2(float lo, float hi) {
    __hip_bfloat162 h2 = __float22bfloat162_rn(make_float2(lo, hi));
    uint u;
    __builtin_memcpy(&u, &h2, sizeof(u));
    return u;
}
__device__ __forceinline__ float relu_(float x) { return fmaxf(x, 0.0f); }
__device__ __forceinline__ float fast_sigmoid(float x) {
    return __builtin_amdgcn_rcpf(1.0f + __expf(-x));
}
__device__ __forceinline__ float dot4r(f32x4 v, float4 w) {
    return fmaf(relu_(v[0]), w.x, fmaf(relu_(v[1]), w.y,
           fmaf(relu_(v[2]), w.z, relu_(v[3]) * w.w)));
}
__device__ __forceinline__ bf16x8 u4bf(uint4 u) {
    bf16x8 r;
    __builtin_memcpy(&r, &u, sizeof(r));
    return r;
}

// ---------------- global max of criticality -> ws[0] (as uint bits) ----------
__global__ __launch_bounds__(256) void crit_max_kernel(
        const float* __restrict__ crit, unsigned int* __restrict__ ws, int n4) {
    __shared__ float smax[4];
    const int tid = threadIdx.x;
    float m = 0.0f;
    const float4* c4 = (const float4*)crit;
    for (int i = blockIdx.x * 256 + tid; i < n4; i += gridDim.x * 256) {
        float4 v = c4[i];
        m = fmaxf(fmaxf(m, v.x), fmaxf(fmaxf(v.y, v.z), v.w));
    }
#pragma unroll
    for (int off = 32; off > 0; off >>= 1)
        m = fmaxf(m, __shfl_xor(m, off));
    if ((tid & 63) == 0) smax[tid >> 6] = m;
    __syncthreads();
    if (tid == 0) {
        m = fmaxf(fmaxf(smax[0], smax[1]), fmaxf(smax[2], smax[3]));
        atomicMax(ws, __float_as_uint(m));
    }
}

// -------- fused MFMA risk kernel: zero-permute layout-matched pipeline -------
// Key idea: element e = ewave + lane stays in lane (g = lane>>4, c = lane&15)
// the whole way. Tile t processes elements t*16+c via B masked to lanes g==t
// with weights replicated at every k-region. Between layers, the C-fragment
// (units 4g+j at lane (g,c)) is packed in place and the NEXT layer's A is
// scattered so A[m][8g+j] = W[4g+j][m] -> no cross-lane moves at all.
__global__ __launch_bounds__(256, 3) void risk_mfma_kernel(
        const float* __restrict__ tp,   const float* __restrict__ crit,
        const float* __restrict__ conn, const float* __restrict__ sens,
        const float* __restrict__ bv,   const float* __restrict__ dsv,
        const float* __restrict__ comp, const float* __restrict__ rt,
        const float* __restrict__ sev,
        const float* __restrict__ ctxW1, const float* __restrict__ ctxb1,
        const float* __restrict__ ctxW2, const float* __restrict__ ctxb2,
        const float* __restrict__ ctxW3, const float* __restrict__ ctxb3,
        const float* __restrict__ pW1,  const float* __restrict__ pb1,
        const float* __restrict__ pW2,  const float* __restrict__ pb2,
        const float* __restrict__ pW3,  const float* __restrict__ pb3,
        const float* __restrict__ pWo,  const float* __restrict__ pbo,
        const float* __restrict__ w_threat, const float* __restrict__ w_impact,
        const float* __restrict__ w_vuln,   const float* __restrict__ w_ctx,
        const unsigned int* __restrict__ ws_max,
        float* __restrict__ out) {
    const int lane = threadIdx.x & 63;
    const int g    = lane >> 4;   // 0..3 (tile ownership)
    const int c    = lane & 15;   // 0..15 (column)

    const bf16x8 z8 = {0,0,0,0,0,0,0,0};
    const f32x4  z4 = {0.f,0.f,0.f,0.f};

    // ---- uniform scalars ----
    const float m   = __uint_as_float(ws_max[0]);
    const float wt  = w_threat[0], wi = w_impact[0], wv = w_vuln[0], wc = w_ctx[0];
    const float inv_tw = 1.0f / (wt + wi + wv + wc);
    const float imul = (m > 0.0f) ? 1.0f / fmaxf(m, 1e-12f) : 1.0f;
    const float wcn = wc * inv_tw;
    const float cb3 = ctxb3[0];
    const float pbo0 = pbo[0];

    // ---- A-operand weight fragments (lane (g,c): A[row=c][k=8g+i]) ----
    // ctx L1 (4->16): k=i (replicated every g-region): W1[i][c], bias at i=4
    bf16x8 cwAll = z8;
    cwAll[0] = bf16s(ctxW1[c]);
    cwAll[1] = bf16s(ctxW1[16 + c]);
    cwAll[2] = bf16s(ctxW1[32 + c]);
    cwAll[3] = bf16s(ctxW1[48 + c]);
    cwAll[4] = bf16s(ctxb1[c]);
    // ctx L2 (16->8): k=8g+i (i<4) <-> unit 4g+i; outputs m=c<8
    bf16x8 cw2All = z8;
    if (c < 8) {
#pragma unroll
        for (int i = 0; i < 4; ++i)
            cw2All[i] = bf16s(ctxW2[(4 * g + i) * 8 + c]);
    }
    // prop L1 (4->64), out-tile nt: feat order [base,-,-,-,1,crit,conn,sens]
    bf16x8 w1All[4];
#pragma unroll
    for (int nt = 0; nt < 4; ++nt) {
        bf16x8 f = z8;
        f[0] = bf16s(pW1[nt * 16 + c]);          // base row
        f[4] = bf16s(pb1[nt * 16 + c]);          // bias (B supplies 1.0)
        f[5] = bf16s(pW1[64 + nt * 16 + c]);     // crit row
        f[6] = bf16s(pW1[128 + nt * 16 + c]);    // conn row
        f[7] = bf16s(pW1[192 + nt * 16 + c]);    // sens row
        w1All[nt] = f;
    }
    // prop L2 (64->32), out-tile mt, k-frag kf: k=8g+i <-> L1 unit
    //   i<4: kf*32 + 4g + i ; i>=4: kf*32 + 16 + 4g + (i-4)
    bf16x8 w2A[2][2];
#pragma unroll
    for (int mt = 0; mt < 2; ++mt)
#pragma unroll
        for (int kf = 0; kf < 2; ++kf) {
            bf16x8 f;
#pragma unroll
            for (int i = 0; i < 4; ++i)
                f[i] = bf16s(pW2[(kf * 32 + 4 * g + i) * 32 + mt * 16 + c]);
#pragma unroll
            for (int i = 4; i < 8; ++i)
                f[i] = bf16s(pW2[(kf * 32 + 16 + 4 * g + (i - 4)) * 32 + mt * 16 + c]);
            w2A[mt][kf] = f;
        }
    // prop L3 (32->16): i<4: unit 4g+i ; i>=4: 16 + 4g + (i-4)
    bf16x8 w3A;
#pragma unroll
    for (int i = 0; i < 4; ++i) w3A[i] = bf16s(pW3[(4 * g + i) * 16 + c]);
#pragma unroll
    for (int i = 4; i < 8; ++i) w3A[i] = bf16s(pW3[(16 + 4 * g + (i - 4)) * 16 + c]);

    // bias / epilogue vectors (C rows m = 4g+j)
    f32x4 b2i[2];
#pragma unroll
    for (int mt = 0; mt < 2; ++mt) {
        float4 t = ((const float4*)pb2)[mt * 4 + g];
        b2i[mt] = (f32x4){t.x, t.y, t.z, t.w};
    }
    float4 t3 = ((const float4*)pb3)[g];
    f32x4 b3i = (f32x4){t3.x, t3.y, t3.z, t3.w};
    f32x4 cb2i = z4;
    float4 cw3v = make_float4(0.f, 0.f, 0.f, 0.f);
    if (g < 2) {
        float4 tb = ((const float4*)ctxb2)[g];
        cb2i = (f32x4){tb.x, tb.y, tb.z, tb.w};
        cw3v = ((const float4*)ctxW3)[g];
    }
    float4 wog = ((const float4*)pWo)[g];

    const int eblock = blockIdx.x * (256 * ITERS);

#pragma unroll 1
    for (int it = 0; it < ITERS; ++it) {
        const int ewave = eblock + it * 256 + (int)(threadIdx.x >> 6) * 64;
        // -------- phase 1: per-element components (element = own lane) -------
        uint4 fv;
        float pbase;
        {
            const int e = ewave + lane;
            float tpv = tp[e], cv = crit[e], cnv = conn[e], snv = sens[e];
            float bvv = bv[e], dvv = dsv[e], cpv = comp[e], rtv = rt[e], svv = sev[e];
            float threat = fast_sigmoid(3.0f * tpv);
            float impact = cv * imul;
            float vuln   = svv * 0.1f;
            float invrt  = __builtin_amdgcn_rcpf(rtv + 1e-6f);
            pbase = (wt * threat + wi * impact + wv * vuln) * inv_tw;
            fv.x = pk2(bvv, dvv);   // k0=bv, k1=dsv
            fv.y = pk2(cpv, invrt); // k2=comp, k3=1/rt
            fv.z = pk2(1.0f, cv);   // k4=1.0(bias), k5=crit
            fv.w = pk2(cnv, snv);   // k6=conn, k7=sens
        }
        // masked per-tile B-frags (nonzero only in lanes g==t)
        uint4 Bt[4];
#pragma unroll
        for (int t = 0; t < 4; ++t) {
            bool sel = (g == t);
            Bt[t].x = sel ? fv.x : 0u;
            Bt[t].y = sel ? fv.y : 0u;
            Bt[t].z = sel ? fv.z : 0u;
            Bt[t].w = sel ? fv.w : 0u;
        }
        // -------- ctx MLP: 4 independent tile chains -------------------------
        float pcv[4];
#pragma unroll
        for (int t = 0; t < 4; ++t) {
            f32x4 cc1 = __builtin_amdgcn_mfma_f32_16x16x32_bf16(cwAll, u4bf(Bt[t]), z4, 0, 0, 0);
            uint4 bu;
            bu.x = pk2(relu_(cc1[0]), relu_(cc1[1]));
            bu.y = pk2(relu_(cc1[2]), relu_(cc1[3]));
            bu.z = 0u;
            bu.w = 0u;
            f32x4 cc2 = __builtin_amdgcn_mfma_f32_16x16x32_bf16(cw2All, u4bf(bu), cb2i, 0, 0, 0);
            pcv[t] = dot4r(cc2, cw3v);
        }
#pragma unroll
        for (int t = 0; t < 4; ++t) {
            pcv[t] += __shfl_xor(pcv[t], 16);
            pcv[t] += __shfl_xor(pcv[t], 32);
        }
        float pcsel = (g == 0) ? pcv[0] : (g == 1) ? pcv[1] : (g == 2) ? pcv[2] : pcv[3];
        float ctxr  = fast_sigmoid(pcsel + cb3);
        float base  = fmaf(wcn, ctxr, pbase);
        uint  bb    = bf16rne(base);
        // -------- prop MLP: 4 independent tile chains ------------------------
        float pv[4];
#pragma unroll
        for (int t = 0; t < 4; ++t) {
            uint4 pB;
            pB.x = (g == t) ? bb : 0u;  // k0=base (k1..3 weights are zero)
            pB.y = Bt[t].y;
            pB.z = Bt[t].z;             // k4=1.0 -> bias, k5=crit
            pB.w = Bt[t].w;             // k6=conn, k7=sens
            bf16x8 bp = u4bf(pB);
            // L1: 4 output-tiles of 16 units
            uint l1p[4][2];
#pragma unroll
            for (int nt = 0; nt < 4; ++nt) {
                f32x4 c1 = __builtin_amdgcn_mfma_f32_16x16x32_bf16(w1All[nt], bp, z4, 0, 0, 0);
                l1p[nt][0] = pk2(relu_(c1[0]), relu_(c1[1]));
                l1p[nt][1] = pk2(relu_(c1[2]), relu_(c1[3]));
            }
            // L2: B-frags assembled for free from packs
            uint4 B0 = make_uint4(l1p[0][0], l1p[0][1], l1p[1][0], l1p[1][1]);
            uint4 B1 = make_uint4(l1p[2][0], l1p[2][1], l1p[3][0], l1p[3][1]);
            bf16x8 b0 = u4bf(B0), b1 = u4bf(B1);
            uint l2p[2][2];
#pragma unroll
            for (int mt = 0; mt < 2; ++mt) {
                f32x4 acc = __builtin_amdgcn_mfma_f32_16x16x32_bf16(w2A[mt][0], b0, b2i[mt], 0, 0, 0);
                f32x4 c2  = __builtin_amdgcn_mfma_f32_16x16x32_bf16(w2A[mt][1], b1, acc, 0, 0, 0);
                l2p[mt][0] = pk2(relu_(c2[0]), relu_(c2[1]));
                l2p[mt][1] = pk2(relu_(c2[2]), relu_(c2[3]));
            }
            // L3
            uint4 B3 = make_uint4(l2p[0][0], l2p[0][1], l2p[1][0], l2p[1][1]);
            f32x4 c3 = __builtin_amdgcn_mfma_f32_16x16x32_bf16(w3A, u4bf(B3), b3i, 0, 0, 0);
            pv[t] = dot4r(c3, wog);
        }
#pragma unroll
        for (int t = 0; t < 4; ++t) {
            pv[t] += __shfl_xor(pv[t], 16);
            pv[t] += __shfl_xor(pv[t], 32);
        }
        float psel = (g == 0) ? pv[0] : (g == 1) ? pv[1] : (g == 2) ? pv[2] : pv[3];
        out[ewave + lane] = fast_sigmoid(psel + pbo0);
    }
}

extern "C" void kernel_launch(void* const* d_in, const int* in_sizes, int n_in,
                              void* d_out, int out_size, void* d_ws, size_t ws_size,
                              hipStream_t stream) {
    const float* tp    = (const float*)d_in[0];
    const float* crit  = (const float*)d_in[1];
    const float* conn  = (const float*)d_in[2];
    const float* sens  = (const float*)d_in[3];
    const float* bv    = (const float*)d_in[4];
    const float* dsv   = (const float*)d_in[5];
    const float* comp  = (const float*)d_in[6];
    const float* rt    = (const float*)d_in[7];
    const float* sev   = (const float*)d_in[8];
    const float* ctxW1 = (const float*)d_in[9];
    const float* ctxb1 = (const float*)d_in[10];
    const float* ctxW2 = (const float*)d_in[11];
    const float* ctxb2 = (const float*)d_in[12];
    const float* ctxW3 = (const float*)d_in[13];
    const float* ctxb3 = (const float*)d_in[14];
    const float* pW1   = (const float*)d_in[15];
    const float* pb1   = (const float*)d_in[16];
    const float* pW2   = (const float*)d_in[17];
    const float* pb2   = (const float*)d_in[18];
    const float* pW3   = (const float*)d_in[19];
    const float* pb3   = (const float*)d_in[20];
    const float* pWo   = (const float*)d_in[21];
    const float* pbo   = (const float*)d_in[22];
    const float* w_t   = (const float*)d_in[23];
    const float* w_i   = (const float*)d_in[24];
    const float* w_v   = (const float*)d_in[25];
    const float* w_c   = (const float*)d_in[26];

    unsigned int* ws_max = (unsigned int*)d_ws;
    float* out = (float*)d_out;

    (void)hipMemsetAsync(ws_max, 0, sizeof(unsigned int), stream);
    crit_max_kernel<<<256, 256, 0, stream>>>(crit, ws_max, TOTAL / 4);
    risk_mfma_kernel<<<BLOCKS, 256, 0, stream>>>(
        tp, crit, conn, sens, bv, dsv, comp, rt, sev,
        ctxW1, ctxb1, ctxW2, ctxb2, ctxW3, ctxb3,
        pW1, pb1, pW2, pb2, pW3, pb3, pWo, pbo,
        w_t, w_i, w_v, w_c, ws_max, out);
}

// Round 8
// 39.343 us; speedup vs baseline: 1.4351x; 1.1295x over previous
//
#include <hip/hip_runtime.h>
#include <hip/hip_bf16.h>

typedef short bf16x8 __attribute__((ext_vector_type(8)));
typedef float f32x4 __attribute__((ext_vector_type(4)));
typedef unsigned int uint;

#define TOTAL (64 * 16384)
#define ITERS 2
#define BLOCKS (TOTAL / (256 * ITERS)) // 2048
#define MAXBLOCKS 256                  // partial-max blocks

__device__ __forceinline__ uint bf16rne(float x) {
    uint b = __float_as_uint(x);
    return (b + 0x7fffu + ((b >> 16) & 1u)) >> 16;
}
__device__ __forceinline__ short bf16s(float x) { return (short)bf16rne(x); }
__device__ __forceinline__ uint pk2(float lo, float hi) {
    __hip_bfloat162 h2 = __float22bfloat162_rn(make_float2(lo, hi));
    uint u;
    __builtin_memcpy(&u, &h2, sizeof(u));
    return u;
}
__device__ __forceinline__ float relu_(float x) { return fmaxf(x, 0.0f); }
__device__ __forceinline__ float fast_sigmoid(float x) {
    return __builtin_amdgcn_rcpf(1.0f + __expf(-x));
}
__device__ __forceinline__ float dot4r(f32x4 v, float4 w) {
    return fmaf(relu_(v[0]), w.x, fmaf(relu_(v[1]), w.y,
           fmaf(relu_(v[2]), w.z, relu_(v[3]) * w.w)));
}
__device__ __forceinline__ bf16x8 u4bf(uint4 u) {
    bf16x8 r;
    __builtin_memcpy(&r, &u, sizeof(r));
    return r;
}

// ------- per-block max of criticality -> ws[blockIdx] (plain store) ----------
__global__ __launch_bounds__(256) void crit_max_kernel(
        const float* __restrict__ crit, float* __restrict__ ws, int n4) {
    __shared__ float smax[4];
    const int tid = threadIdx.x;
    float m = 0.0f;
    const float4* c4 = (const float4*)crit;
    for (int i = blockIdx.x * 256 + tid; i < n4; i += gridDim.x * 256) {
        float4 v = c4[i];
        m = fmaxf(fmaxf(m, v.x), fmaxf(fmaxf(v.y, v.z), v.w));
    }
#pragma unroll
    for (int off = 32; off > 0; off >>= 1)
        m = fmaxf(m, __shfl_xor(m, off));
    if ((tid & 63) == 0) smax[tid >> 6] = m;
    __syncthreads();
    if (tid == 0)
        ws[blockIdx.x] = fmaxf(fmaxf(smax[0], smax[1]), fmaxf(smax[2], smax[3]));
}

// -------- fused MFMA risk kernel: zero-permute layout-matched pipeline -------
__global__ __launch_bounds__(256, 3) void risk_mfma_kernel(
        const float* __restrict__ tp,   const float* __restrict__ crit,
        const float* __restrict__ conn, const float* __restrict__ sens,
        const float* __restrict__ bv,   const float* __restrict__ dsv,
        const float* __restrict__ comp, const float* __restrict__ rt,
        const float* __restrict__ sev,
        const float* __restrict__ ctxW1, const float* __restrict__ ctxb1,
        const float* __restrict__ ctxW2, const float* __restrict__ ctxb2,
        const float* __restrict__ ctxW3, const float* __restrict__ ctxb3,
        const float* __restrict__ pW1,  const float* __restrict__ pb1,
        const float* __restrict__ pW2,  const float* __restrict__ pb2,
        const float* __restrict__ pW3,  const float* __restrict__ pb3,
        const float* __restrict__ pWo,  const float* __restrict__ pbo,
        const float* __restrict__ w_threat, const float* __restrict__ w_impact,
        const float* __restrict__ w_vuln,   const float* __restrict__ w_ctx,
        const float* __restrict__ ws_part,
        float* __restrict__ out) {
    const int lane = threadIdx.x & 63;
    const int g    = lane >> 4;   // 0..3 (tile ownership)
    const int c    = lane & 15;   // 0..15 (column)

    const bf16x8 z8 = {0,0,0,0,0,0,0,0};
    const f32x4  z4 = {0.f,0.f,0.f,0.f};

    // ---- global max from 256 partials (wave-redundant, ~negligible) ----
    float m;
    {
        float4 pm4 = ((const float4*)ws_part)[lane];
        float pm = fmaxf(fmaxf(pm4.x, pm4.y), fmaxf(pm4.z, pm4.w));
#pragma unroll
        for (int off = 32; off > 0; off >>= 1)
            pm = fmaxf(pm, __shfl_xor(pm, off));
        m = pm;
    }

    // ---- uniform scalars ----
    const float wt  = w_threat[0], wi = w_impact[0], wv = w_vuln[0], wc = w_ctx[0];
    const float inv_tw = 1.0f / (wt + wi + wv + wc);
    const float imul = (m > 0.0f) ? 1.0f / fmaxf(m, 1e-12f) : 1.0f;
    const float wcn = wc * inv_tw;
    const float cb3 = ctxb3[0];
    const float pbo0 = pbo[0];

    // ---- A-operand weight fragments (lane (g,c): A[row=c][k=8g+i]) ----
    bf16x8 cwAll = z8;
    cwAll[0] = bf16s(ctxW1[c]);
    cwAll[1] = bf16s(ctxW1[16 + c]);
    cwAll[2] = bf16s(ctxW1[32 + c]);
    cwAll[3] = bf16s(ctxW1[48 + c]);
    cwAll[4] = bf16s(ctxb1[c]);
    bf16x8 cw2All = z8;
    if (c < 8) {
#pragma unroll
        for (int i = 0; i < 4; ++i)
            cw2All[i] = bf16s(ctxW2[(4 * g + i) * 8 + c]);
    }
    bf16x8 w1All[4];
#pragma unroll
    for (int nt = 0; nt < 4; ++nt) {
        bf16x8 f = z8;
        f[0] = bf16s(pW1[nt * 16 + c]);
        f[4] = bf16s(pb1[nt * 16 + c]);
        f[5] = bf16s(pW1[64 + nt * 16 + c]);
        f[6] = bf16s(pW1[128 + nt * 16 + c]);
        f[7] = bf16s(pW1[192 + nt * 16 + c]);
        w1All[nt] = f;
    }
    bf16x8 w2A[2][2];
#pragma unroll
    for (int mt = 0; mt < 2; ++mt)
#pragma unroll
        for (int kf = 0; kf < 2; ++kf) {
            bf16x8 f;
#pragma unroll
            for (int i = 0; i < 4; ++i)
                f[i] = bf16s(pW2[(kf * 32 + 4 * g + i) * 32 + mt * 16 + c]);
#pragma unroll
            for (int i = 4; i < 8; ++i)
                f[i] = bf16s(pW2[(kf * 32 + 16 + 4 * g + (i - 4)) * 32 + mt * 16 + c]);
            w2A[mt][kf] = f;
        }
    bf16x8 w3A;
#pragma unroll
    for (int i = 0; i < 4; ++i) w3A[i] = bf16s(pW3[(4 * g + i) * 16 + c]);
#pragma unroll
    for (int i = 4; i < 8; ++i) w3A[i] = bf16s(pW3[(16 + 4 * g + (i - 4)) * 16 + c]);

    f32x4 b2i[2];
#pragma unroll
    for (int mt = 0; mt < 2; ++mt) {
        float4 t = ((const float4*)pb2)[mt * 4 + g];
        b2i[mt] = (f32x4){t.x, t.y, t.z, t.w};
    }
    float4 t3 = ((const float4*)pb3)[g];
    f32x4 b3i = (f32x4){t3.x, t3.y, t3.z, t3.w};
    f32x4 cb2i = z4;
    float4 cw3v = make_float4(0.f, 0.f, 0.f, 0.f);
    if (g < 2) {
        float4 tb = ((const float4*)ctxb2)[g];
        cb2i = (f32x4){tb.x, tb.y, tb.z, tb.w};
        cw3v = ((const float4*)ctxW3)[g];
    }
    float4 wog = ((const float4*)pWo)[g];

    const int eblock = blockIdx.x * (256 * ITERS);

#pragma unroll 1
    for (int it = 0; it < ITERS; ++it) {
        const int ewave = eblock + it * 256 + (int)(threadIdx.x >> 6) * 64;
        // -------- phase 1: per-element components (element = own lane) -------
        uint4 fv;
        float pbase;
        {
            const int e = ewave + lane;
            float tpv = tp[e], cv = crit[e], cnv = conn[e], snv = sens[e];
            float bvv = bv[e], dvv = dsv[e], cpv = comp[e], rtv = rt[e], svv = sev[e];
            float threat = fast_sigmoid(3.0f * tpv);
            float impact = cv * imul;
            float vuln   = svv * 0.1f;
            float invrt  = __builtin_amdgcn_rcpf(rtv + 1e-6f);
            pbase = (wt * threat + wi * impact + wv * vuln) * inv_tw;
            fv.x = pk2(bvv, dvv);
            fv.y = pk2(cpv, invrt);
            fv.z = pk2(1.0f, cv);
            fv.w = pk2(cnv, snv);
        }
        uint4 Bt[4];
#pragma unroll
        for (int t = 0; t < 4; ++t) {
            bool sel = (g == t);
            Bt[t].x = sel ? fv.x : 0u;
            Bt[t].y = sel ? fv.y : 0u;
            Bt[t].z = sel ? fv.z : 0u;
            Bt[t].w = sel ? fv.w : 0u;
        }
        // -------- ctx MLP: 4 independent tile chains -------------------------
        float pcv[4];
#pragma unroll
        for (int t = 0; t < 4; ++t) {
            f32x4 cc1 = __builtin_amdgcn_mfma_f32_16x16x32_bf16(cwAll, u4bf(Bt[t]), z4, 0, 0, 0);
            uint4 bu;
            bu.x = pk2(relu_(cc1[0]), relu_(cc1[1]));
            bu.y = pk2(relu_(cc1[2]), relu_(cc1[3]));
            bu.z = 0u;
            bu.w = 0u;
            f32x4 cc2 = __builtin_amdgcn_mfma_f32_16x16x32_bf16(cw2All, u4bf(bu), cb2i, 0, 0, 0);
            pcv[t] = dot4r(cc2, cw3v);
        }
#pragma unroll
        for (int t = 0; t < 4; ++t) {
            pcv[t] += __shfl_xor(pcv[t], 16);
            pcv[t] += __shfl_xor(pcv[t], 32);
        }
        float pcsel = (g == 0) ? pcv[0] : (g == 1) ? pcv[1] : (g == 2) ? pcv[2] : pcv[3];
        float ctxr  = fast_sigmoid(pcsel + cb3);
        float base  = fmaf(wcn, ctxr, pbase);
        uint  bb    = bf16rne(base);
        // -------- prop MLP: 4 independent tile chains ------------------------
        float pv[4];
#pragma unroll
        for (int t = 0; t < 4; ++t) {
            uint4 pB;
            pB.x = (g == t) ? bb : 0u;
            pB.y = Bt[t].y;
            pB.z = Bt[t].z;
            pB.w = Bt[t].w;
            bf16x8 bp = u4bf(pB);
            uint l1p[4][2];
#pragma unroll
            for (int nt = 0; nt < 4; ++nt) {
                f32x4 c1 = __builtin_amdgcn_mfma_f32_16x16x32_bf16(w1All[nt], bp, z4, 0, 0, 0);
                l1p[nt][0] = pk2(relu_(c1[0]), relu_(c1[1]));
                l1p[nt][1] = pk2(relu_(c1[2]), relu_(c1[3]));
            }
            uint4 B0 = make_uint4(l1p[0][0], l1p[0][1], l1p[1][0], l1p[1][1]);
            uint4 B1 = make_uint4(l1p[2][0], l1p[2][1], l1p[3][0], l1p[3][1]);
            bf16x8 b0 = u4bf(B0), b1 = u4bf(B1);
            uint l2p[2][2];
#pragma unroll
            for (int mt = 0; mt < 2; ++mt) {
                f32x4 acc = __builtin_amdgcn_mfma_f32_16x16x32_bf16(w2A[mt][0], b0, b2i[mt], 0, 0, 0);
                f32x4 c2  = __builtin_amdgcn_mfma_f32_16x16x32_bf16(w2A[mt][1], b1, acc, 0, 0, 0);
                l2p[mt][0] = pk2(relu_(c2[0]), relu_(c2[1]));
                l2p[mt][1] = pk2(relu_(c2[2]), relu_(c2[3]));
            }
            uint4 B3 = make_uint4(l2p[0][0], l2p[0][1], l2p[1][0], l2p[1][1]);
            f32x4 c3 = __builtin_amdgcn_mfma_f32_16x16x32_bf16(w3A, u4bf(B3), b3i, 0, 0, 0);
            pv[t] = dot4r(c3, wog);
        }
#pragma unroll
        for (int t = 0; t < 4; ++t) {
            pv[t] += __shfl_xor(pv[t], 16);
            pv[t] += __shfl_xor(pv[t], 32);
        }
        float psel = (g == 0) ? pv[0] : (g == 1) ? pv[1] : (g == 2) ? pv[2] : pv[3];
        out[ewave + lane] = fast_sigmoid(psel + pbo0);
    }
}

extern "C" void kernel_launch(void* const* d_in, const int* in_sizes, int n_in,
                              void* d_out, int out_size, void* d_ws, size_t ws_size,
                              hipStream_t stream) {
    const float* tp    = (const float*)d_in[0];
    const float* crit  = (const float*)d_in[1];
    const float* conn  = (const float*)d_in[2];
    const float* sens  = (const float*)d_in[3];
    const float* bv    = (const float*)d_in[4];
    const float* dsv   = (const float*)d_in[5];
    const float* comp  = (const float*)d_in[6];
    const float* rt    = (const float*)d_in[7];
    const float* sev   = (const float*)d_in[8];
    const float* ctxW1 = (const float*)d_in[9];
    const float* ctxb1 = (const float*)d_in[10];
    const float* ctxW2 = (const float*)d_in[11];
    const float* ctxb2 = (const float*)d_in[12];
    const float* ctxW3 = (const float*)d_in[13];
    const float* ctxb3 = (const float*)d_in[14];
    const float* pW1   = (const float*)d_in[15];
    const float* pb1   = (const float*)d_in[16];
    const float* pW2   = (const float*)d_in[17];
    const float* pb2   = (const float*)d_in[18];
    const float* pW3   = (const float*)d_in[19];
    const float* pb3   = (const float*)d_in[20];
    const float* pWo   = (const float*)d_in[21];
    const float* pbo   = (const float*)d_in[22];
    const float* w_t   = (const float*)d_in[23];
    const float* w_i   = (const float*)d_in[24];
    const float* w_v   = (const float*)d_in[25];
    const float* w_c   = (const float*)d_in[26];

    float* ws_part = (float*)d_ws;
    float* out = (float*)d_out;

    crit_max_kernel<<<MAXBLOCKS, 256, 0, stream>>>(crit, ws_part, TOTAL / 4);
    risk_mfma_kernel<<<BLOCKS, 256, 0, stream>>>(
        tp, crit, conn, sens, bv, dsv, comp, rt, sev,
        ctxW1, ctxb1, ctxW2, ctxb2, ctxW3, ctxb3,
        pW1, pb1, pW2, pb2, pW3, pb3, pWo, pbo,
        w_t, w_i, w_v, w_c, ws_part, out);
}